// Round 11
// baseline (21603.612 us; speedup 1.0000x reference)
//
#include <hip/hip_runtime.h>
#include <hip/hip_bf16.h>
#include <math.h>

#define B_  128
#define T_  256
#define DIN 512
#define H_  1024

typedef __attribute__((ext_vector_type(8))) short bf16x8;
typedef __attribute__((ext_vector_type(4))) float f32x4;

#define GLD_LDS16(gsrc, ldst) \
  __builtin_amdgcn_global_load_lds((const __attribute__((address_space(1))) void*)(gsrc), \
                                   (__attribute__((address_space(3))) void*)(ldst), 16, 0, 0)

__device__ __forceinline__ void split_bf16(float v, __hip_bfloat16* hi, __hip_bfloat16* lo) {
    __hip_bfloat16 h = __float2bfloat16(v);
    *hi = h;
    *lo = __float2bfloat16(v - __bfloat162float(h));
}

__device__ __forceinline__ float sigmoidf_(float x) { return 1.f / (1.f + expf(-x)); }

// ---- coherent (L3-served) helpers ----
__device__ __forceinline__ void cohld1_issue(float* dst, const float* ptr) {
    asm volatile("global_load_dword %0, %1, off sc0 sc1" : "=v"(*dst) : "v"(ptr));
}
__device__ __forceinline__ void cohst1(float* ptr, float v) {
    asm volatile("global_store_dword %0, %1, off sc0 sc1" :: "v"(ptr), "v"(v) : "memory");
}
__device__ __forceinline__ void cohst_u16(unsigned short* ptr, unsigned int v) {
    asm volatile("global_store_short %0, %1, off sc0 sc1" :: "v"(ptr), "v"(v) : "memory");
}
__device__ __forceinline__ void cohst_split(unsigned short* hip_, unsigned short* lop_, float v) {
    __hip_bfloat16 h, lo2;
    split_bf16(v, &h, &lo2);
    cohst_u16(hip_, *(unsigned short*)&h);
    cohst_u16(lop_, *(unsigned short*)&lo2);
}
#define COH_WAIT() do { asm volatile("s_waitcnt vmcnt(0)" ::: "memory"); \
                        __builtin_amdgcn_sched_barrier(0); } while (0)

#define AADD(pp) __hip_atomic_fetch_add((pp), 1u, __ATOMIC_RELAXED, __HIP_MEMORY_SCOPE_AGENT)
#define ALOAD(pp) __hip_atomic_load((pp), __ATOMIC_RELAXED, __HIP_MEMORY_SCOPE_AGENT)

// --------------------------- small prep kernels ----------------------------
__global__ void bsum_perm_k(const float* __restrict__ bi, const float* __restrict__ bh,
                            float* __restrict__ o) {
    int c = blockIdx.x * 256 + threadIdx.x;            // 4096, permuted c = j*4+g
    int srow = ((c & 3) << 10) | (c >> 2);
    o[c] = bi[srow] + bh[srow];
}

__global__ void detect_mask_k(const int* __restrict__ m, int nwords, int* __restrict__ flag) {
    __shared__ int bad;
    if (threadIdx.x == 0) bad = 0;
    __syncthreads();
    for (int i = threadIdx.x; i < nwords; i += blockDim.x) {
        unsigned v = (unsigned)m[i];
        if (v > 1u) bad = 1;
    }
    __syncthreads();
    if (threadIdx.x == 0) flag[0] = bad ? 0 : 1;  // 1 => int32, 0 => u8
}

__global__ void cvt_split_k(const float* __restrict__ s, __hip_bfloat16* __restrict__ hi,
                            __hip_bfloat16* __restrict__ lo, int n) {
    int i = blockIdx.x * 256 + threadIdx.x;
    if (i < n) split_bf16(s[i], hi + i, lo + i);
}

__global__ void wgp_split_k(const float* __restrict__ Wih, const float* __restrict__ Whh,
                            __hip_bfloat16* __restrict__ Wh, __hip_bfloat16* __restrict__ Wl) {
    long i = (long)blockIdx.x * 256 + threadIdx.x;     // 4096*1536
    int c = (int)(i / 1536), k = (int)(i - (long)c * 1536);
    int srow = ((c & 3) << 10) | (c >> 2);
    float v = (k < DIN) ? Wih[(long)srow * DIN + k] : Whh[(long)srow * H_ + (k - DIN)];
    split_bf16(v, Wh + i, Wl + i);
}

__global__ void cvtx_k(const float* __restrict__ xsrc, __hip_bfloat16* __restrict__ xh,
                       __hip_bfloat16* __restrict__ xl) {
    int i = blockIdx.x * 256 + threadIdx.x;
    int b = i >> 9, c = i & 511;
    split_bf16(xsrc[(long)b * (T_ * DIN) + c], xh + i, xl + i);
}

// --------------------------- GEMM cores ------------------------------------
constexpr int APL = 128 * 64 * 2;          // 16 KB per A plane
constexpr int BPL = 32 * 64 * 2;           // 4 KB per B plane
constexpr int BUFB = 2 * APL + 2 * BPL;    // 40 KB
constexpr int LDSZ = 3 * BUFB;             // 120 KB -> 1 block/CU

// plain-staged core (operands crossed >=1 kernel boundary). BN=32, 2x2 waves.
// leaves acc[4], n0_, wm_, wn_ in scope.
#define GEMM_CORE(NT, NB, KSP, A1H, A1L, LDA1, K1V, A2H, A2L, LDA2, WHP, WLP, LDW) \
    const int n0_ = (NB) * 32; \
    const int kbase_ = (KSP) * ((NT) * 64); \
    const int wm_ = (w >> 1) * 64, wn_ = (w & 1) * 16; \
    auto stage = [&](int buf, int kt) { \
        char* base = lds + buf * BUFB; \
        const int kb = kbase_ + kt * 64; \
        _Pragma("unroll") \
        for (int pp = 0; pp < 2; ++pp) { \
            const __hip_bfloat16* A1 = pp ? (A1L) : (A1H); \
            const __hip_bfloat16* A2 = pp ? (A2L) : (A2H); \
            _Pragma("unroll") \
            for (int j = 0; j < 4; ++j) { \
                int c = j * 256 + tid; \
                int row = c >> 3, sl2 = c & 7; \
                int e = kb + ((sl2 ^ (row & 7)) << 3); \
                const __hip_bfloat16* src = (e < (K1V)) ? (A1 + (long)row * (LDA1) + e) \
                                                        : (A2 + (long)row * (LDA2) + (e - (K1V))); \
                GLD_LDS16(src, base + pp * APL + ((j * 256 + (tid & 192)) << 4)); \
            } \
            { \
                int row = tid >> 3, sl2 = tid & 7; \
                int e = kb + ((sl2 ^ (row & 7)) << 3); \
                const __hip_bfloat16* src = (pp ? (WLP) : (WHP)) + (long)(n0_ + row) * (LDW) + e; \
                GLD_LDS16(src, base + 2 * APL + pp * BPL + ((tid & 192) << 4)); \
            } \
        } \
    }; \
    f32x4 acc[4] = {}; \
    stage(0, 0); \
    if ((NT) > 1) stage(1, 1); \
    for (int kt = 0; kt < (NT); ++kt) { \
        if (kt + 1 < (NT)) asm volatile("s_waitcnt vmcnt(10)" ::: "memory"); \
        else               asm volatile("s_waitcnt vmcnt(0)"  ::: "memory"); \
        __builtin_amdgcn_s_barrier(); \
        __builtin_amdgcn_sched_barrier(0); \
        if (kt + 2 < (NT)) stage((kt + 2) % 3, kt + 2); \
        const char* base = lds + (kt % 3) * BUFB; \
        _Pragma("unroll") \
        for (int ks = 0; ks < 2; ++ks) { \
            bf16x8 afh[4], afl[4], bh, bl; \
            _Pragma("unroll") \
            for (int mi = 0; mi < 4; ++mi) { \
                int row = wm_ + mi * 16 + (l & 15); \
                int sl2 = (l >> 4) + ks * 4; \
                int off = row * 128 + ((sl2 ^ (row & 7)) << 4); \
                afh[mi] = *(const bf16x8*)(base + off); \
                afl[mi] = *(const bf16x8*)(base + APL + off); \
            } \
            { \
                int row = wn_ + (l & 15); \
                int sl2 = (l >> 4) + ks * 4; \
                int off = row * 128 + ((sl2 ^ (row & 7)) << 4); \
                bh = *(const bf16x8*)(base + 2 * APL + off); \
                bl = *(const bf16x8*)(base + 2 * APL + BPL + off); \
            } \
            _Pragma("unroll") \
            for (int mi = 0; mi < 4; ++mi) { \
                acc[mi] = __builtin_amdgcn_mfma_f32_16x16x32_bf16(afh[mi], bh, acc[mi], 0, 0, 0); \
                acc[mi] = __builtin_amdgcn_mfma_f32_16x16x32_bf16(afl[mi], bh, acc[mi], 0, 0, 0); \
                acc[mi] = __builtin_amdgcn_mfma_f32_16x16x32_bf16(afh[mi], bl, acc[mi], 0, 0, 0); \
            } \
        } \
    }

// coherent-A core (A written sc0sc1 earlier in the SAME dispatch). Single A
// operand, BN=32. reg-stage A via sc0sc1 dwordx4 -> ds_write (round-9 proven).
#define GEMM_CORE_COH(NT, NB, KSP, AH, AL, LDA, WHP, WLP, LDW) \
    const int n0_ = (NB) * 32; \
    const int kbase_ = (KSP) * ((NT) * 64); \
    const int wm_ = (w >> 1) * 64, wn_ = (w & 1) * 16; \
    uint4 rA[2][4]; \
    auto issueA = [&](int kt) { \
        const int kb = kbase_ + kt * 64; \
        _Pragma("unroll") \
        for (int pp = 0; pp < 2; ++pp) { \
            const unsigned short* Ap = (const unsigned short*)(pp ? (AL) : (AH)); \
            _Pragma("unroll") \
            for (int j = 0; j < 4; ++j) { \
                int c = j * 256 + tid; \
                int row = c >> 3, sl2 = c & 7; \
                int e = kb + ((sl2 ^ (row & 7)) << 3); \
                const unsigned short* src = Ap + (long)row * (LDA) + e; \
                asm volatile("global_load_dwordx4 %0, %1, off sc0 sc1" \
                             : "=v"(rA[pp][j]) : "v"(src)); \
            } \
        } \
    }; \
    auto writeA = [&](int buf) { \
        char* wb = lds + buf * BUFB; \
        _Pragma("unroll") \
        for (int pp = 0; pp < 2; ++pp) \
            _Pragma("unroll") \
            for (int j = 0; j < 4; ++j) \
                *(uint4*)(wb + pp * APL + (j * 256 + tid) * 16) = rA[pp][j]; \
    }; \
    auto issueB = [&](int kt, int buf) { \
        char* bb = lds + buf * BUFB; \
        const int kb = kbase_ + kt * 64; \
        int row = tid >> 3, sl2 = tid & 7; \
        int e = kb + ((sl2 ^ (row & 7)) << 3); \
        _Pragma("unroll") \
        for (int pp = 0; pp < 2; ++pp) { \
            const __hip_bfloat16* src = (pp ? (WLP) : (WHP)) + (long)(n0_ + row) * (LDW) + e; \
            GLD_LDS16(src, bb + 2 * APL + pp * BPL + ((tid & 192) << 4)); \
        } \
    }; \
    f32x4 acc[4] = {}; \
    issueA(0); issueB(0, 0); \
    asm volatile("s_waitcnt vmcnt(2)" ::: "memory"); \
    __builtin_amdgcn_sched_barrier(0); \
    writeA(0); \
    issueA(1); issueB(1, 1); \
    for (int kt = 0; kt < (NT); ++kt) { \
        asm volatile("s_waitcnt vmcnt(0) lgkmcnt(0)" ::: "memory"); \
        __builtin_amdgcn_s_barrier(); \
        __builtin_amdgcn_sched_barrier(0); \
        if (kt + 1 < (NT)) writeA((kt + 1) % 3); \
        if (kt + 2 < (NT)) { issueA(kt + 2); issueB(kt + 2, (kt + 2) % 3); } \
        const char* base = lds + (kt % 3) * BUFB; \
        _Pragma("unroll") \
        for (int ks = 0; ks < 2; ++ks) { \
            bf16x8 afh[4], afl[4], bh, bl; \
            _Pragma("unroll") \
            for (int mi = 0; mi < 4; ++mi) { \
                int row = wm_ + mi * 16 + (l & 15); \
                int sl2 = (l >> 4) + ks * 4; \
                int off = row * 128 + ((sl2 ^ (row & 7)) << 4); \
                afh[mi] = *(const bf16x8*)(base + off); \
                afl[mi] = *(const bf16x8*)(base + APL + off); \
            } \
            { \
                int row = wn_ + (l & 15); \
                int sl2 = (l >> 4) + ks * 4; \
                int off = row * 128 + ((sl2 ^ (row & 7)) << 4); \
                bh = *(const bf16x8*)(base + 2 * APL + off); \
                bl = *(const bf16x8*)(base + 2 * APL + BPL + off); \
            } \
            _Pragma("unroll") \
            for (int mi = 0; mi < 4; ++mi) { \
                acc[mi] = __builtin_amdgcn_mfma_f32_16x16x32_bf16(afh[mi], bh, acc[mi], 0, 0, 0); \
                acc[mi] = __builtin_amdgcn_mfma_f32_16x16x32_bf16(afl[mi], bh, acc[mi], 0, 0, 0); \
                acc[mi] = __builtin_amdgcn_mfma_f32_16x16x32_bf16(afh[mi], bl, acc[mi], 0, 0, 0); \
            } \
        } \
    }

// --------------------------- node 1: G + cell + Q --------------------------
// blocks 0-127: G ksp0 (K [0,768)) + partner reduce + cell -> hy (coh) + x-split
// blocks 128-255: G ksp1 (K [768,1536)) -> partial (coh) + flag; then Q.
__global__ __launch_bounds__(256)
void node1_k(const __hip_bfloat16* __restrict__ xh, const __hip_bfloat16* __restrict__ xl,
             const __hip_bfloat16* __restrict__ hh, const __hip_bfloat16* __restrict__ hl,
             const __hip_bfloat16* __restrict__ Wgh, const __hip_bfloat16* __restrict__ Wgl,
             const __hip_bfloat16* __restrict__ Wah, const __hip_bfloat16* __restrict__ Wal,
             const float* __restrict__ bsump, float* __restrict__ cbuf,
             unsigned short* __restrict__ AoBh, unsigned short* __restrict__ AoBl,
             float* __restrict__ gpart, float* __restrict__ qpart,
             unsigned* __restrict__ gflag, unsigned* __restrict__ hcnt,
             float* __restrict__ cf,
             const float* __restrict__ input, int t,
             __hip_bfloat16* __restrict__ nxh, __hip_bfloat16* __restrict__ nxl)
{
    __shared__ __attribute__((aligned(16))) char lds[LDSZ];
    const int blk = blockIdx.x, tid = threadIdx.x;
    const int l = tid & 63, w = tid >> 6;

    if (blk < 128) {
        const int ct = blk;
        GEMM_CORE(12, ct, 0, xh, xl, DIN, DIN, hh, hl, H_, Wgh, Wgl, (DIN + H_));

        // wait partner partial
        if (tid == 0) while (ALOAD(&gflag[t * 128 + ct]) < 1u) __builtin_amdgcn_s_sleep(2);
        __syncthreads();

        float pv[4][4];
        #pragma unroll
        for (int mi = 0; mi < 4; ++mi) {
            int rb = wm_ + mi * 16 + (l >> 4) * 4;
            int col = wn_ + (l & 15);
            #pragma unroll
            for (int r = 0; r < 4; ++r)
                cohld1_issue(&pv[mi][r], gpart + ct * 4096 + (rb + r) * 32 + col);
        }
        COH_WAIT();

        // stage full gates into LDS (reuse), padded stride 36
        float* sg = (float*)lds;
        {
            float bv = bsump[n0_ + wn_ + (l & 15)];
            #pragma unroll
            for (int mi = 0; mi < 4; ++mi) {
                int rb = wm_ + mi * 16 + (l >> 4) * 4;
                int col = wn_ + (l & 15);
                #pragma unroll
                for (int r = 0; r < 4; ++r)
                    sg[(rb + r) * 36 + col] = acc[mi][r] + pv[mi][r] + bv;
            }
        }
        __syncthreads();

        #pragma unroll
        for (int k = 0; k < 4; ++k) {
            int ci = k * 256 + tid;                 // 1024 cells: 128 b x 8 j
            int b = ci >> 3, jp = ci & 7;
            float4 g4 = *(const float4*)&sg[b * 36 + jp * 4];   // i,f,g,o
            int j = ct * 8 + jp;
            long idx = (long)b * H_ + j;
            float ig = sigmoidf_(g4.x);
            float fg = sigmoidf_(g4.y);
            float gg = tanhf(g4.z);
            float og = sigmoidf_(g4.w);
            float c = fg * cbuf[idx] + ig * gg;
            float h = og * tanhf(c);
            cbuf[idx] = c;
            cohst_split(AoBh + (long)b * 2048 + 1024 + j,
                        AoBl + (long)b * 2048 + 1024 + j, h);
            if (cf) cf[idx] = c;
        }
        COH_WAIT();
        __syncthreads();
        if (tid == 0) AADD(&hcnt[t]);

        // x(t+1) split (plain; consumed next launch)
        if (t + 1 < T_) {
            #pragma unroll
            for (int k = 0; k < 2; ++k) {
                int i2 = blk * 512 + k * 256 + tid;
                int b2 = i2 >> 9, col = i2 & 511;
                float v = input[((long)b2 * T_ + (t + 1)) * DIN + col];
                split_bf16(v, nxh + i2, nxl + i2);
            }
        }
    } else {
        const int ct = blk - 128;
        {
            GEMM_CORE(12, ct, 1, xh, xl, DIN, DIN, hh, hl, H_, Wgh, Wgl, (DIN + H_));
            #pragma unroll
            for (int mi = 0; mi < 4; ++mi) {
                int rb = wm_ + mi * 16 + (l >> 4) * 4;
                int col = wn_ + (l & 15);
                #pragma unroll
                for (int r = 0; r < 4; ++r)
                    cohst1(gpart + ct * 4096 + (rb + r) * 32 + col, acc[mi][r]);
            }
            COH_WAIT();
            __syncthreads();
            if (tid == 0) AADD(&gflag[t * 128 + ct]);
        }

        // wait all hy, then Q: hy @ Wa^T, Ksplit=4, NT=4 (coh A)
        if (tid == 0) while (ALOAD(&hcnt[t]) < 128u) __builtin_amdgcn_s_sleep(2);
        __syncthreads();
        {
            const int qct = ct & 31, qksp = ct >> 5;
            GEMM_CORE_COH(4, qct, qksp,
                          ((const unsigned short*)AoBh + H_), ((const unsigned short*)AoBl + H_),
                          (2 * H_), Wah, Wal, H_);
            float* Cb = qpart + (long)qksp * (B_ * H_);
            const int n = n0_ + wn_ + (l & 15);
            #pragma unroll
            for (int mi = 0; mi < 4; ++mi) {
                int rb = wm_ + mi * 16 + (l >> 4) * 4;
                #pragma unroll
                for (int r = 0; r < 4; ++r)
                    Cb[(long)(rb + r) * H_ + n] = acc[mi][r];
            }
        }
    }
}

// --------------------------- node 2: A + O + tanh --------------------------
// blocks 0-127: attention b=blk -> wctx (coh) + wcnt
// blocks 128-255: O (32 ct x 4 ksp, NT=8). ksp2/3: hy half plain (boundary);
// ksp0/1: poll wcnt, wctx half coh. ksp1-3 post partials; ksp0 reduces+tanh.
__global__ __launch_bounds__(256)
void node2_k(const float* __restrict__ ctx, const float* __restrict__ qpart,
             const void* __restrict__ maskp, const int* __restrict__ mflag,
             const __hip_bfloat16* __restrict__ Woh, const __hip_bfloat16* __restrict__ Wol,
             unsigned short* __restrict__ AoBh, unsigned short* __restrict__ AoBl,
             float* __restrict__ opart,
             unsigned* __restrict__ wcnt, unsigned* __restrict__ ocnt,
             __hip_bfloat16* __restrict__ hth, __hip_bfloat16* __restrict__ htl,
             float* __restrict__ out, int t, float* __restrict__ hf)
{
    __shared__ __attribute__((aligned(16))) char lds[LDSZ];
    const int blk = blockIdx.x, tid = threadIdx.x;
    const int l = tid & 63, w = tid >> 6;

    if (blk < 128) {
        // ---- attention, lane owns cols [l*16, l*16+16) ----
        const int b = blk;
        const float* cb = ctx + (long)b * (T_ * H_);
        const int mode = mflag[0];

        float rq[16];
        #pragma unroll
        for (int j = 0; j < 16; ++j) {
            long o = (long)b * H_ + l * 16 + j;
            rq[j] = qpart[o] + qpart[o + 131072] + qpart[o + 262144] + qpart[o + 393216];
        }

        float m = -INFINITY, s = 0.f, acc[16] = {};
        for (int li = w; li < T_; li += 4) {
            bool msk = mode ? (((const int*)maskp)[b * T_ + li] != 0)
                            : (((const unsigned char*)maskp)[b * T_ + li] != 0);
            if (msk) continue;
            const float4* cr4 = (const float4*)(cb + (long)li * H_ + l * 16);
            float4 v0 = cr4[0], v1 = cr4[1], v2 = cr4[2], v3 = cr4[3];
            float rc[16] = { v0.x, v0.y, v0.z, v0.w, v1.x, v1.y, v1.z, v1.w,
                             v2.x, v2.y, v2.z, v2.w, v3.x, v3.y, v3.z, v3.w };
            float d = 0.f;
            #pragma unroll
            for (int j = 0; j < 16; ++j) d += rc[j] * rq[j];
            #pragma unroll
            for (int off = 1; off < 64; off <<= 1) d += __shfl_xor(d, off);
            float mn = fmaxf(m, d);
            float f = expf(m - mn);
            float pp = expf(d - mn);
            s = s * f + pp;
            #pragma unroll
            for (int j = 0; j < 16; ++j) acc[j] = acc[j] * f + pp * rc[j];
            m = mn;
        }

        float (*sacc)[H_] = (float (*)[H_])lds;
        float (*sms)[2] = (float (*)[2])(lds + 4 * H_ * sizeof(float));
        #pragma unroll
        for (int j = 0; j < 16; ++j) sacc[w][l * 16 + j] = acc[j];
        if (l == 0) { sms[w][0] = m; sms[w][1] = s; }
        __syncthreads();

        float M = fmaxf(fmaxf(sms[0][0], sms[1][0]), fmaxf(sms[2][0], sms[3][0]));
        float fw[4], S = 0.f;
        #pragma unroll
        for (int ww = 0; ww < 4; ++ww) {
            fw[ww] = (sms[ww][0] == -INFINITY) ? 0.f : expf(sms[ww][0] - M);
            S += fw[ww] * sms[ww][1];
        }
        float inv = 1.f / S;
        for (int k = tid; k < H_; k += 256) {
            float a = (sacc[0][k] * fw[0] + sacc[1][k] * fw[1] +
                       sacc[2][k] * fw[2] + sacc[3][k] * fw[3]) * inv;
            cohst_split(AoBh + (long)b * 2048 + k, AoBl + (long)b * 2048 + k, a);
        }
        COH_WAIT();
        __syncthreads();
        if (tid == 0) AADD(&wcnt[t]);
    } else {
        const int idx = blk - 128;
        const int ct = idx & 31, ksp = idx >> 5;

        if (ksp >= 2) {
            // hy half (K [1024,2048)): plain staging (crossed node boundary)
            GEMM_CORE(8, ct, ksp,
                      (const __hip_bfloat16*)AoBh, (const __hip_bfloat16*)AoBl,
                      (2 * H_), (4 * H_),
                      (const __hip_bfloat16*)AoBh, (const __hip_bfloat16*)AoBl, (2 * H_),
                      Woh, Wol, (2 * H_));
            #pragma unroll
            for (int mi = 0; mi < 4; ++mi) {
                int rb = wm_ + mi * 16 + (l >> 4) * 4;
                int col = wn_ + (l & 15);
                #pragma unroll
                for (int r = 0; r < 4; ++r)
                    cohst1(opart + (long)(ksp - 1) * 131072 + ct * 4096 + (rb + r) * 32 + col,
                           acc[mi][r]);
            }
            COH_WAIT();
            __syncthreads();
            if (tid == 0) AADD(&ocnt[t * 32 + ct]);
        } else {
            // wctx half (K [0,1024)): wait attention, coherent staging
            if (tid == 0) while (ALOAD(&wcnt[t]) < 128u) __builtin_amdgcn_s_sleep(2);
            __syncthreads();
            GEMM_CORE_COH(8, ct, ksp,
                          (const unsigned short*)AoBh, (const unsigned short*)AoBl,
                          (2 * H_), Woh, Wol, (2 * H_));
            if (ksp == 1) {
                #pragma unroll
                for (int mi = 0; mi < 4; ++mi) {
                    int rb = wm_ + mi * 16 + (l >> 4) * 4;
                    int col = wn_ + (l & 15);
                    #pragma unroll
                    for (int r = 0; r < 4; ++r)
                        cohst1(opart + ct * 4096 + (rb + r) * 32 + col, acc[mi][r]);
                }
                COH_WAIT();
                __syncthreads();
                if (tid == 0) AADD(&ocnt[t * 32 + ct]);
            } else {
                // ksp0: gather 3 partials, reduce, tanh, split, store outputs
                if (tid == 0) while (ALOAD(&ocnt[t * 32 + ct]) < 3u) __builtin_amdgcn_s_sleep(2);
                __syncthreads();
                float pv[3][4][4];
                #pragma unroll
                for (int q = 0; q < 3; ++q)
                    #pragma unroll
                    for (int mi = 0; mi < 4; ++mi) {
                        int rb = wm_ + mi * 16 + (l >> 4) * 4;
                        int col = wn_ + (l & 15);
                        #pragma unroll
                        for (int r = 0; r < 4; ++r)
                            cohld1_issue(&pv[q][mi][r],
                                opart + (long)q * 131072 + ct * 4096 + (rb + r) * 32 + col);
                    }
                COH_WAIT();
                const int j = n0_ + wn_ + (l & 15);
                #pragma unroll
                for (int mi = 0; mi < 4; ++mi) {
                    int rb = wm_ + mi * 16 + (l >> 4) * 4;
                    #pragma unroll
                    for (int r = 0; r < 4; ++r) {
                        int b = rb + r;
                        float v = acc[mi][r] + pv[0][mi][r] + pv[1][mi][r] + pv[2][mi][r];
                        v = tanhf(v);
                        split_bf16(v, hth + (long)b * H_ + j, htl + (long)b * H_ + j);
                        out[(long)b * (T_ * H_) + (long)t * H_ + j] = v;
                        if (hf) hf[(long)b * H_ + j] = v;
                    }
                }
            }
        }
    }
}

// --------------------------- launcher --------------------------------------
extern "C" void kernel_launch(void* const* d_in, const int* in_sizes, int n_in,
                              void* d_out, int out_size, void* d_ws, size_t ws_size,
                              hipStream_t stream)
{
    const float* input  = (const float*)d_in[0];
    const float* h0     = (const float*)d_in[1];
    const float* c0     = (const float*)d_in[2];
    const float* ctx    = (const float*)d_in[3];
    const void*  srcmask= d_in[4];
    const float* W_ih   = (const float*)d_in[5];
    const float* W_hh   = (const float*)d_in[6];
    const float* b_ih   = (const float*)d_in[7];
    const float* b_hh   = (const float*)d_in[8];
    const float* W_attn = (const float*)d_in[9];
    const float* W_out  = (const float*)d_in[10];

    constexpr int B = B_, T = T_, D = DIN, H = H_;

    // -------- workspace --------
    float* f = (float*)d_ws;
    float* bsump = f; f += 4 * H;
    float* cbuf  = f; f += (size_t)B * H;
    float* gpart = f; f += (size_t)128 * 4096;         // per-colTile partials
    float* qpart = f; f += (size_t)4 * B * H;
    float* opart = f; f += (size_t)3 * 32 * 4096;
    int*   mflag = (int*)f; f += 64;
    unsigned* gflag = (unsigned*)f; f += 32768;        // [T][128]
    unsigned* hcnt  = (unsigned*)f; f += 256;          // [T]
    unsigned* wcnt  = (unsigned*)f; f += 256;          // [T]
    unsigned* ocnt  = (unsigned*)f; f += 8192;         // [T][32]
    __hip_bfloat16* p = (__hip_bfloat16*)f;
    __hip_bfloat16* Wgh = p; p += (size_t)4 * H * (D + H);
    __hip_bfloat16* Wgl = p; p += (size_t)4 * H * (D + H);
    __hip_bfloat16* Wah = p; p += (size_t)H * H;
    __hip_bfloat16* Wal = p; p += (size_t)H * H;
    __hip_bfloat16* Woh = p; p += (size_t)H * 2 * H;
    __hip_bfloat16* Wol = p; p += (size_t)H * 2 * H;
    __hip_bfloat16* hth = p; p += (size_t)B * H;       // h_tilde hi (recurrent)
    __hip_bfloat16* htl = p; p += (size_t)B * H;
    __hip_bfloat16* AoBh = p; p += (size_t)B * 2 * H;  // [wctx | hy] hi
    __hip_bfloat16* AoBl = p; p += (size_t)B * 2 * H;
    __hip_bfloat16* xth[2], *xtl[2];
    xth[0] = p; p += (size_t)B * D;
    xtl[0] = p; p += (size_t)B * D;
    xth[1] = p; p += (size_t)B * D;
    xtl[1] = p; p += (size_t)B * D;

    float* out = (float*)d_out;
    float* hf  = out + (size_t)B * T * H;
    float* cf  = hf + (size_t)B * H;

    // -------- prep --------
    hipMemsetAsync(gflag, 0, (32768 + 256 + 256 + 8192) * sizeof(unsigned), stream);
    hipMemcpyAsync(cbuf, c0, (size_t)B * H * sizeof(float), hipMemcpyDeviceToDevice, stream);
    bsum_perm_k<<<dim3(16), dim3(256), 0, stream>>>(b_ih, b_hh, bsump);
    detect_mask_k<<<dim3(1), dim3(256), 0, stream>>>((const int*)srcmask, B * T / 4, mflag);
    wgp_split_k<<<dim3(4 * H * (D + H) / 256), dim3(256), 0, stream>>>(W_ih, W_hh, Wgh, Wgl);
    cvt_split_k<<<dim3(H * H / 256), dim3(256), 0, stream>>>(W_attn, Wah, Wal, H * H);
    cvt_split_k<<<dim3(H * 2 * H / 256), dim3(256), 0, stream>>>(W_out, Woh, Wol, H * 2 * H);
    cvt_split_k<<<dim3(B * H / 256), dim3(256), 0, stream>>>(h0, hth, htl, B * H);
    cvtx_k<<<dim3(B * D / 256), dim3(256), 0, stream>>>(input, xth[0], xtl[0]);

    dim3 blk(256);
    for (int t = 0; t < T; ++t) {
        int sl = t & 1, sn = sl ^ 1;

        node1_k<<<dim3(256), blk, 0, stream>>>(
            xth[sl], xtl[sl], hth, htl, Wgh, Wgl, Wah, Wal, bsump, cbuf,
            (unsigned short*)AoBh, (unsigned short*)AoBl,
            gpart, qpart, gflag, hcnt,
            (t == T - 1) ? cf : nullptr,
            input, t, xth[sn], xtl[sn]);

        node2_k<<<dim3(256), blk, 0, stream>>>(
            ctx, qpart, srcmask, mflag, Woh, Wol,
            (unsigned short*)AoBh, (unsigned short*)AoBl,
            opart, wcnt, ocnt, hth, htl,
            out, t, (t == T - 1) ? hf : nullptr);
    }
}

// Round 12
// 19361.456 us; speedup vs baseline: 1.1158x; 1.1158x over previous
//
#include <hip/hip_runtime.h>
#include <hip/hip_bf16.h>
#include <math.h>

#define B_  128
#define T_  256
#define DIN 512
#define H_  1024

typedef __attribute__((ext_vector_type(8))) short bf16x8;
typedef __attribute__((ext_vector_type(4))) float f32x4;

#define GLD_LDS16(gsrc, ldst) \
  __builtin_amdgcn_global_load_lds((const __attribute__((address_space(1))) void*)(gsrc), \
                                   (__attribute__((address_space(3))) void*)(ldst), 16, 0, 0)

#define WAITVM_(n) asm volatile("s_waitcnt vmcnt(" #n ")" ::: "memory")
#define WAITVM(n) WAITVM_(n)

__device__ __forceinline__ void split_bf16(float v, __hip_bfloat16* hi, __hip_bfloat16* lo) {
    __hip_bfloat16 h = __float2bfloat16(v);
    *hi = h;
    *lo = __float2bfloat16(v - __bfloat162float(h));
}

__device__ __forceinline__ float sigmoidf_(float x) { return 1.f / (1.f + expf(-x)); }

// --------------------------- small prep kernels ----------------------------
__global__ void bsum_perm_k(const float* __restrict__ bi, const float* __restrict__ bh,
                            float* __restrict__ o) {
    int c = blockIdx.x * 256 + threadIdx.x;            // 4096, permuted c = j*4+g
    int srow = ((c & 3) << 10) | (c >> 2);
    o[c] = bi[srow] + bh[srow];
}

__global__ void detect_mask_k(const int* __restrict__ m, int nwords, int* __restrict__ flag) {
    __shared__ int bad;
    if (threadIdx.x == 0) bad = 0;
    __syncthreads();
    for (int i = threadIdx.x; i < nwords; i += blockDim.x) {
        unsigned v = (unsigned)m[i];
        if (v > 1u) bad = 1;
    }
    __syncthreads();
    if (threadIdx.x == 0) flag[0] = bad ? 0 : 1;  // 1 => int32, 0 => u8
}

__global__ void cvt_split_k(const float* __restrict__ s, __hip_bfloat16* __restrict__ hi,
                            __hip_bfloat16* __restrict__ lo, int n) {
    int i = blockIdx.x * 256 + threadIdx.x;
    if (i < n) split_bf16(s[i], hi + i, lo + i);
}

// permuted W_ih: row c=j*4+g -> [4096][512] hi/lo planes
__global__ void wihp_split_k(const float* __restrict__ Wih,
                             __hip_bfloat16* __restrict__ Wh, __hip_bfloat16* __restrict__ Wl) {
    long i = (long)blockIdx.x * 256 + threadIdx.x;     // 4096*512
    int c = (int)(i >> 9), k = (int)(i & 511);
    int srow = ((c & 3) << 10) | (c >> 2);
    split_bf16(Wih[(long)srow * DIN + k], Wh + i, Wl + i);
}

// permuted W_hh: row c=j*4+g -> [4096][1024] hi/lo planes
__global__ void whhp_split_k(const float* __restrict__ Whh,
                             __hip_bfloat16* __restrict__ Wh, __hip_bfloat16* __restrict__ Wl) {
    long i = (long)blockIdx.x * 256 + threadIdx.x;     // 4096*1024
    int c = (int)(i >> 10), k = (int)(i & 1023);
    int srow = ((c & 3) << 10) | (c >> 2);
    split_bf16(Whh[(long)srow * H_ + k], Wh + i, Wl + i);
}

// x slice [128][512] for step t -> hi/lo planes
__global__ void cvtx_k(const float* __restrict__ input, int t,
                       __hip_bfloat16* __restrict__ xh, __hip_bfloat16* __restrict__ xl) {
    int i = blockIdx.x * 256 + threadIdx.x;
    int b = i >> 9, c = i & 511;
    split_bf16(input[((long)b * T_ + t) * DIN + c], xh + i, xl + i);
}

// --------------------------- GEMM core (round-10 proven) -------------------
constexpr int APL = 128 * 64 * 2;          // 16 KB per A plane
constexpr int BPL = 32 * 64 * 2;           // 4 KB per B plane slot
constexpr int BUFB = 2 * APL + 2 * BPL;    // 40 KB
constexpr int LDSZ = 3 * BUFB;             // 120 KB

// plane-fused split-bf16 GEMM core (hh, lh, hl): leaves acc/n0_/wm_/wn_ in scope.
#define GEMM_CORE(NT, NW2, BNV, VMID, NB, KSP, A1H, A1L, LDA1, K1V, A2H, A2L, LDA2, WHP, WLP, LDW) \
    const int n0_ = (NB) * (BNV); \
    const int kbase_ = (KSP) * ((NT) * 64); \
    const int wm_ = (NW2) ? (w >> 1) * 64 : w * 32; \
    const int wn_ = (NW2) ? (w & 1) * 16 : 0; \
    auto stage = [&](int buf, int kt) { \
        char* base = lds + buf * BUFB; \
        const int kb = kbase_ + kt * 64; \
        _Pragma("unroll") \
        for (int pp = 0; pp < 2; ++pp) { \
            const __hip_bfloat16* A1 = pp ? (A1L) : (A1H); \
            const __hip_bfloat16* A2 = pp ? (A2L) : (A2H); \
            _Pragma("unroll") \
            for (int j = 0; j < 4; ++j) { \
                int c = j * 256 + tid; \
                int row = c >> 3, sl2 = c & 7; \
                int e = kb + ((sl2 ^ (row & 7)) << 3); \
                const __hip_bfloat16* src = (e < (K1V)) ? (A1 + (long)row * (LDA1) + e) \
                                                        : (A2 + (long)row * (LDA2) + (e - (K1V))); \
                GLD_LDS16(src, base + pp * APL + ((j * 256 + (tid & 192)) << 4)); \
            } \
            if (tid < (BNV) * 8) { \
                int row = tid >> 3, sl2 = tid & 7; \
                int e = kb + ((sl2 ^ (row & 7)) << 3); \
                const __hip_bfloat16* src = (pp ? (WLP) : (WHP)) + (long)(n0_ + row) * (LDW) + e; \
                GLD_LDS16(src, base + 2 * APL + pp * BPL + ((tid & 192) << 4)); \
            } \
        } \
    }; \
    f32x4 acc[4] = {}; \
    stage(0, 0); \
    if ((NT) > 1) stage(1, 1); \
    for (int kt = 0; kt < (NT); ++kt) { \
        if (kt + 1 < (NT)) { WAITVM(VMID); } else { WAITVM(0); } \
        __builtin_amdgcn_s_barrier(); \
        __builtin_amdgcn_sched_barrier(0); \
        if (kt + 2 < (NT)) stage((kt + 2) % 3, kt + 2); \
        const char* base = lds + (kt % 3) * BUFB; \
        _Pragma("unroll") \
        for (int ks = 0; ks < 2; ++ks) { \
            bf16x8 afh[4], afl[4], bh, bl; \
            _Pragma("unroll") \
            for (int mi = 0; mi < ((NW2) ? 4 : 2); ++mi) { \
                int row = wm_ + mi * 16 + (l & 15); \
                int sl2 = (l >> 4) + ks * 4; \
                int off = row * 128 + ((sl2 ^ (row & 7)) << 4); \
                afh[mi] = *(const bf16x8*)(base + off); \
                afl[mi] = *(const bf16x8*)(base + APL + off); \
            } \
            { \
                int row = wn_ + (l & 15); \
                int sl2 = (l >> 4) + ks * 4; \
                int off = row * 128 + ((sl2 ^ (row & 7)) << 4); \
                bh = *(const bf16x8*)(base + 2 * APL + off); \
                bl = *(const bf16x8*)(base + 2 * APL + BPL + off); \
            } \
            _Pragma("unroll") \
            for (int mi = 0; mi < ((NW2) ? 4 : 2); ++mi) { \
                acc[mi] = __builtin_amdgcn_mfma_f32_16x16x32_bf16(afh[mi], bh, acc[mi], 0, 0, 0); \
                acc[mi] = __builtin_amdgcn_mfma_f32_16x16x32_bf16(afl[mi], bh, acc[mi], 0, 0, 0); \
                acc[mi] = __builtin_amdgcn_mfma_f32_16x16x32_bf16(afh[mi], bl, acc[mi], 0, 0, 0); \
            } \
        } \
    }

// --------------------------- xpart GEMM body -------------------------------
// xpart[b][cperm] = x_t[b,:] @ Wih_perm^T  (K=512, NT=8, BN=32, 128 blocks)
__device__ __forceinline__ void xpart_body(char* lds, int ct, int tid, int l, int w,
                                           const __hip_bfloat16* xh, const __hip_bfloat16* xl,
                                           const __hip_bfloat16* Wih_h, const __hip_bfloat16* Wih_l,
                                           float* xp)
{
    GEMM_CORE(8, 1, 32, 10, ct, 0, xh, xl, DIN, DIN, xh, xl, DIN, Wih_h, Wih_l, DIN);
    const int n = n0_ + wn_ + (l & 15);
    #pragma unroll
    for (int mi = 0; mi < 4; ++mi) {
        int rb = wm_ + mi * 16 + (l >> 4) * 4;
        #pragma unroll
        for (int r = 0; r < 4; ++r)
            xp[(long)(rb + r) * 4096 + n] = acc[mi][r];
    }
}

__global__ __launch_bounds__(256)
void xpart_k(const __hip_bfloat16* __restrict__ xh, const __hip_bfloat16* __restrict__ xl,
             const __hip_bfloat16* __restrict__ Wih_h, const __hip_bfloat16* __restrict__ Wih_l,
             float* __restrict__ xp)
{
    __shared__ __attribute__((aligned(16))) char lds[LDSZ];
    const int tid = threadIdx.x, l = tid & 63, w = tid >> 6;
    xpart_body(lds, blockIdx.x, tid, l, w, xh, xl, Wih_h, Wih_l, xp);
}

// --------------------------- N1: gates-h GEMM + fused cell -----------------
// blocks 0-127: h-recurrence GEMM (K=1024, NT=16, permuted cols) + cell
// blocks 128-255: split x(t+1) into planes (for N3's xpart(t+1))
__global__ __launch_bounds__(256)
void n1_k(const __hip_bfloat16* __restrict__ hh, const __hip_bfloat16* __restrict__ hl,
          const __hip_bfloat16* __restrict__ Whh_h, const __hip_bfloat16* __restrict__ Whh_l,
          const float* __restrict__ bsump, const float* __restrict__ xpart,
          float* __restrict__ cbuf,
          __hip_bfloat16* __restrict__ AoBh, __hip_bfloat16* __restrict__ AoBl,
          float* __restrict__ cf,
          const float* __restrict__ input, int t,
          __hip_bfloat16* __restrict__ nxh, __hip_bfloat16* __restrict__ nxl)
{
    __shared__ __attribute__((aligned(16))) char lds[LDSZ];
    const int blk = blockIdx.x, tid = threadIdx.x;
    const int l = tid & 63, w = tid >> 6;

    if (blk < 128) {
        GEMM_CORE(16, 1, 32, 10, blk, 0, hh, hl, H_, H_, hh, hl, H_, Whh_h, Whh_l, H_);

        __syncthreads();
        float* sg = (float*)lds;                    // [128][36] padded
        {
            int colg = n0_ + wn_ + (l & 15);
            int coll = wn_ + (l & 15);
            float bv = bsump[colg];
            #pragma unroll
            for (int mi = 0; mi < 4; ++mi) {
                int rb = wm_ + mi * 16 + (l >> 4) * 4;
                #pragma unroll
                for (int r = 0; r < 4; ++r)
                    sg[(rb + r) * 36 + coll] = acc[mi][r] + xpart[(long)(rb + r) * 4096 + colg] + bv;
            }
        }
        __syncthreads();

        #pragma unroll
        for (int k = 0; k < 4; ++k) {
            int ci = k * 256 + tid;                 // 1024 cells: 128 b x 8 j
            int b = ci >> 3, jp = ci & 7;
            float4 g4 = *(const float4*)&sg[b * 36 + jp * 4];   // i,f,g,o
            int j = blk * 8 + jp;
            long idx = (long)b * H_ + j;
            float ig = sigmoidf_(g4.x);
            float fg = sigmoidf_(g4.y);
            float gg = tanhf(g4.z);
            float og = sigmoidf_(g4.w);
            float c = fg * cbuf[idx] + ig * gg;
            float h = og * tanhf(c);
            cbuf[idx] = c;
            split_bf16(h, AoBh + (long)b * 2048 + 1024 + j, AoBl + (long)b * 2048 + 1024 + j);
            if (cf) cf[idx] = c;
        }
    } else if (t + 1 < T_) {
        #pragma unroll
        for (int k = 0; k < 2; ++k) {
            int i2 = (blk - 128) * 512 + k * 256 + tid;
            int b2 = i2 >> 9, col = i2 & 511;
            float v = input[((long)b2 * T_ + (t + 1)) * DIN + col];
            split_bf16(v, nxh + i2, nxl + i2);
        }
    }
}

// --------------------------- N2: q partials || O-hy partials ---------------
__global__ __launch_bounds__(256)
void n2_k(const __hip_bfloat16* __restrict__ AoBh, const __hip_bfloat16* __restrict__ AoBl,
          const __hip_bfloat16* __restrict__ Wah, const __hip_bfloat16* __restrict__ Wal,
          const __hip_bfloat16* __restrict__ Woh, const __hip_bfloat16* __restrict__ Wol,
          float* __restrict__ qpart, float* __restrict__ opart)
{
    __shared__ __attribute__((aligned(16))) char lds[LDSZ];
    const int blk = blockIdx.x, tid = threadIdx.x;
    const int l = tid & 63, w = tid >> 6;

    if (blk < 128) {
        const int ct = blk & 31, ksp = blk >> 5;
        GEMM_CORE(4, 1, 32, 10, ct, ksp,
                  (AoBh + H_), (AoBl + H_), (2 * H_), (2 * H_),
                  (AoBh + H_), (AoBl + H_), (2 * H_), Wah, Wal, H_);
        float* Cb = qpart + (long)ksp * (B_ * H_);
        const int n = n0_ + wn_ + (l & 15);
        #pragma unroll
        for (int mi = 0; mi < 4; ++mi) {
            int rb = wm_ + mi * 16 + (l >> 4) * 4;
            #pragma unroll
            for (int r = 0; r < 4; ++r)
                Cb[(long)(rb + r) * H_ + n] = acc[mi][r];
        }
    } else {
        const int ct = (blk - 128) & 31, ksp = (blk - 128) >> 5;
        GEMM_CORE(4, 1, 32, 10, ct, ksp,
                  (AoBh + H_), (AoBl + H_), (2 * H_), (4 * H_),
                  (AoBh + H_), (AoBl + H_), (2 * H_),
                  (Woh + H_), (Wol + H_), (2 * H_));
        float* Cb = opart + (long)ksp * (B_ * H_);
        const int n = n0_ + wn_ + (l & 15);
        #pragma unroll
        for (int mi = 0; mi < 4; ++mi) {
            int rb = wm_ + mi * 16 + (l >> 4) * 4;
            #pragma unroll
            for (int r = 0; r < 4; ++r)
                Cb[(long)(rb + r) * H_ + n] = acc[mi][r];
        }
    }
}

// --------------------------- N3: attention || xpart(t+1) -------------------
__global__ __launch_bounds__(256)
void n3_k(const float* __restrict__ ctx, const float* __restrict__ qpart,
          const void* __restrict__ maskp, const int* __restrict__ mflag,
          __hip_bfloat16* __restrict__ AoBh, __hip_bfloat16* __restrict__ AoBl,
          const __hip_bfloat16* __restrict__ nxh, const __hip_bfloat16* __restrict__ nxl,
          const __hip_bfloat16* __restrict__ Wih_h, const __hip_bfloat16* __restrict__ Wih_l,
          float* __restrict__ xpnext, int last)
{
    __shared__ __attribute__((aligned(16))) char lds[LDSZ];
    const int blk = blockIdx.x, tid = threadIdx.x;
    const int l = tid & 63, w = tid >> 6;

    if (blk < 128) {
        const int b = blk;
        const float* cb = ctx + (long)b * (T_ * H_);
        const int mode = mflag[0];

        float rq[16];
        #pragma unroll
        for (int j = 0; j < 16; ++j) {
            long o = (long)b * H_ + l + j * 64;
            rq[j] = qpart[o] + qpart[o + 131072] + qpart[o + 262144] + qpart[o + 393216];
        }

        float m = -INFINITY, s = 0.f, acc[16] = {};
        for (int li = w; li < T_; li += 4) {
            bool msk = mode ? (((const int*)maskp)[b * T_ + li] != 0)
                            : (((const unsigned char*)maskp)[b * T_ + li] != 0);
            if (msk) continue;
            const float* cr = cb + (long)li * H_;
            float rc[16], d = 0.f;
            #pragma unroll
            for (int j = 0; j < 16; ++j) { rc[j] = cr[l + j * 64]; d += rc[j] * rq[j]; }
            #pragma unroll
            for (int off = 1; off < 64; off <<= 1) d += __shfl_xor(d, off);
            float mn = fmaxf(m, d);
            float f = expf(m - mn);
            float p = expf(d - mn);
            s = s * f + p;
            #pragma unroll
            for (int j = 0; j < 16; ++j) acc[j] = acc[j] * f + p * rc[j];
            m = mn;
        }

        float (*sacc)[H_] = (float (*)[H_])lds;
        float (*sms)[2] = (float (*)[2])(lds + 4 * H_ * sizeof(float));
        #pragma unroll
        for (int j = 0; j < 16; ++j) sacc[w][l + j * 64] = acc[j];
        if (l == 0) { sms[w][0] = m; sms[w][1] = s; }
        __syncthreads();

        float M = fmaxf(fmaxf(sms[0][0], sms[1][0]), fmaxf(sms[2][0], sms[3][0]));
        float fw[4], S = 0.f;
        #pragma unroll
        for (int ww = 0; ww < 4; ++ww) {
            fw[ww] = (sms[ww][0] == -INFINITY) ? 0.f : expf(sms[ww][0] - M);
            S += fw[ww] * sms[ww][1];
        }
        float inv = 1.f / S;
        for (int k = tid; k < H_; k += 256) {
            float a = (sacc[0][k] * fw[0] + sacc[1][k] * fw[1] +
                       sacc[2][k] * fw[2] + sacc[3][k] * fw[3]) * inv;
            split_bf16(a, AoBh + (long)b * 2048 + k, AoBl + (long)b * 2048 + k);
        }
    } else if (!last) {
        xpart_body(lds, blk - 128, tid, l, w, nxh, nxl, Wih_h, Wih_l, xpnext);
    }
}

// --------------------------- N4: O-wctx GEMM + fused finish ----------------
// 64 blocks, BN=16, K=1024 (wctx half), NT=16. Epilogue adds 4 hy-partials,
// tanh, split -> h_tilde planes, out slice, (h_f).
__global__ __launch_bounds__(256)
void n4_k(const __hip_bfloat16* __restrict__ AoBh, const __hip_bfloat16* __restrict__ AoBl,
          const __hip_bfloat16* __restrict__ Woh, const __hip_bfloat16* __restrict__ Wol,
          const float* __restrict__ opart,
          __hip_bfloat16* __restrict__ hth, __hip_bfloat16* __restrict__ htl,
          float* __restrict__ out, int t, float* __restrict__ hf)
{
    __shared__ __attribute__((aligned(16))) char lds[LDSZ];
    const int tid = threadIdx.x;
    const int l = tid & 63, w = tid >> 6;

    GEMM_CORE(16, 0, 16, 8, (int)blockIdx.x, 0,
              AoBh, AoBl, (2 * H_), (2 * H_),
              AoBh, AoBl, (2 * H_), Woh, Wol, (2 * H_));

    const int j = n0_ + (l & 15);
    #pragma unroll
    for (int mi = 0; mi < 2; ++mi) {
        int bbase = wm_ + mi * 16 + (l >> 4) * 4;
        #pragma unroll
        for (int r = 0; r < 4; ++r) {
            int b = bbase + r;
            long o = (long)b * H_ + j;
            float v = acc[mi][r] + opart[o] + opart[o + 131072]
                                + opart[o + 262144] + opart[o + 393216];
            v = tanhf(v);
            split_bf16(v, hth + o, htl + o);
            out[(long)b * (T_ * H_) + (long)t * H_ + j] = v;
            if (hf) hf[o] = v;
        }
    }
}

// --------------------------- launcher --------------------------------------
extern "C" void kernel_launch(void* const* d_in, const int* in_sizes, int n_in,
                              void* d_out, int out_size, void* d_ws, size_t ws_size,
                              hipStream_t stream)
{
    const float* input  = (const float*)d_in[0];
    const float* h0     = (const float*)d_in[1];
    const float* c0     = (const float*)d_in[2];
    const float* ctx    = (const float*)d_in[3];
    const void*  srcmask= d_in[4];
    const float* W_ih   = (const float*)d_in[5];
    const float* W_hh   = (const float*)d_in[6];
    const float* b_ih   = (const float*)d_in[7];
    const float* b_hh   = (const float*)d_in[8];
    const float* W_attn = (const float*)d_in[9];
    const float* W_out  = (const float*)d_in[10];

    constexpr int B = B_, T = T_, D = DIN, H = H_;

    // -------- workspace (~54 MB) --------
    float* f = (float*)d_ws;
    float* bsump = f; f += 4 * H;
    float* cbuf  = f; f += (size_t)B * H;
    float* qpart = f; f += (size_t)4 * B * H;
    float* opart = f; f += (size_t)4 * B * H;
    float* xpart0 = f; f += (size_t)B * 4 * H;
    float* xpart1 = f; f += (size_t)B * 4 * H;
    int*   mflag = (int*)f; f += 64;
    __hip_bfloat16* p = (__hip_bfloat16*)f;
    __hip_bfloat16* Wihh = p; p += (size_t)4 * H * D;
    __hip_bfloat16* Wihl = p; p += (size_t)4 * H * D;
    __hip_bfloat16* Whhh = p; p += (size_t)4 * H * H;
    __hip_bfloat16* Whhl = p; p += (size_t)4 * H * H;
    __hip_bfloat16* Wah = p; p += (size_t)H * H;
    __hip_bfloat16* Wal = p; p += (size_t)H * H;
    __hip_bfloat16* Woh = p; p += (size_t)H * 2 * H;
    __hip_bfloat16* Wol = p; p += (size_t)H * 2 * H;
    __hip_bfloat16* hth = p; p += (size_t)B * H;       // h_tilde hi (recurrent)
    __hip_bfloat16* htl = p; p += (size_t)B * H;
    __hip_bfloat16* AoBh = p; p += (size_t)B * 2 * H;  // [wctx | hy] hi
    __hip_bfloat16* AoBl = p; p += (size_t)B * 2 * H;
    __hip_bfloat16* xph[2], *xpl[2];
    xph[0] = p; p += (size_t)B * D;
    xpl[0] = p; p += (size_t)B * D;
    xph[1] = p; p += (size_t)B * D;
    xpl[1] = p; p += (size_t)B * D;

    float* out = (float*)d_out;
    float* hf  = out + (size_t)B * T * H;
    float* cf  = hf + (size_t)B * H;

    // -------- prep --------
    hipMemcpyAsync(cbuf, c0, (size_t)B * H * sizeof(float), hipMemcpyDeviceToDevice, stream);
    bsum_perm_k<<<dim3(16), dim3(256), 0, stream>>>(b_ih, b_hh, bsump);
    detect_mask_k<<<dim3(1), dim3(256), 0, stream>>>((const int*)srcmask, B * T / 4, mflag);
    wihp_split_k<<<dim3(4 * H * D / 256), dim3(256), 0, stream>>>(W_ih, Wihh, Wihl);
    whhp_split_k<<<dim3(4 * H * H / 256), dim3(256), 0, stream>>>(W_hh, Whhh, Whhl);
    cvt_split_k<<<dim3(H * H / 256), dim3(256), 0, stream>>>(W_attn, Wah, Wal, H * H);
    cvt_split_k<<<dim3(H * 2 * H / 256), dim3(256), 0, stream>>>(W_out, Woh, Wol, H * 2 * H);
    cvt_split_k<<<dim3(B * H / 256), dim3(256), 0, stream>>>(h0, hth, htl, B * H);
    // bootstrap: x(0) planes + xpart(0)
    cvtx_k<<<dim3(B * D / 256), dim3(256), 0, stream>>>(input, 0, xph[0], xpl[0]);
    xpart_k<<<dim3(128), dim3(256), 0, stream>>>(xph[0], xpl[0], Wihh, Wihl, xpart0);

    dim3 blk(256);
    for (int t = 0; t < T; ++t) {
        float* xp_cur  = (t & 1) ? xpart1 : xpart0;
        float* xp_next = (t & 1) ? xpart0 : xpart1;
        int sn = (t + 1) & 1;

        // N1: gates-h GEMM + cell (+ x(t+1) split on idle blocks)
        n1_k<<<dim3(256), blk, 0, stream>>>(
            hth, htl, Whhh, Whhl, bsump, xp_cur, cbuf,
            AoBh, AoBl, (t == T - 1) ? cf : nullptr,
            input, t, xph[sn], xpl[sn]);

        // N2: q partials || O-hy partials
        n2_k<<<dim3(256), blk, 0, stream>>>(AoBh, AoBl, Wah, Wal, Woh, Wol, qpart, opart);

        // N3: attention || xpart(t+1)
        n3_k<<<dim3(256), blk, 0, stream>>>(
            ctx, qpart, srcmask, mflag, AoBh, AoBl,
            xph[sn], xpl[sn], Wihh, Wihl, xp_next, (t == T - 1) ? 1 : 0);

        // N4: O-wctx GEMM + fused reduce/tanh/split
        n4_k<<<dim3(64), blk, 0, stream>>>(
            AoBh, AoBl, Woh, Wol, opart, hth, htl,
            out, t, (t == T - 1) ? hf : nullptr);
    }
}